// Round 10
// baseline (60051.605 us; speedup 1.0000x reference)
//
#include <hip/hip_runtime.h>
#include <hip/hip_bf16.h>
#include <stdint.h>

constexpr int kSEQ = 8192;
constexpr int kIN  = 1024;
constexpr int kH   = 2048;
constexpr int kG4  = 4 * kH;   // 8192 gate rows
constexpr int kNB  = 256;      // persistent workgroups (1 per CU)
constexpr int kHB  = kH / kNB; // 8 h-values owned per WG
constexpr int kWP  = kH + 16;  // LDS weight row stride

// ---- workspace layout (bytes) ----
constexpr size_t OFF_HBUF  = 0;          // u64 hbuf[2][kH]  (32 KB) tagged h words
constexpr size_t OFF_ABORT = 32768;      // uint32 abort flag
constexpr size_t OFF_HS    = 65536;      // bf16 hs[kSEQ][kH]   (32 MB)
constexpr size_t OFF_XP    = OFF_HS + (size_t)kSEQ * kH * 2; // bf16 xp[kSEQ][kG4] (128 MB)

__device__ __forceinline__ float bflo(uint32_t v) { return __uint_as_float(v << 16); }
__device__ __forceinline__ float bfhi(uint32_t v) { return __uint_as_float(v & 0xffff0000u); }

// ---------------------------------------------------------------------------
// Kernel 1: x_proj[m][n] = sum_k input[m][k] * W_ih[n][k] + b_ih[n] + b_hh[n]
// fp32 LDS-tiled GEMM, 64x64 tile, BK=16, 256 threads, 4x4 per thread.
// ---------------------------------------------------------------------------
__global__ __launch_bounds__(256) void k_xproj(const float* __restrict__ A,
                                               const float* __restrict__ B,
                                               const float* __restrict__ bih,
                                               const float* __restrict__ bhh,
                                               __hip_bfloat16* __restrict__ C)
{
    __shared__ float As[16][65];
    __shared__ float Bs[16][65];

    const int bx = blockIdx.x & 127;   // n tile
    const int by = blockIdx.x >> 7;    // m tile
    const int tid = threadIdx.x;
    const int r  = tid >> 2;           // 0..63 row within tile
    const int kq = (tid & 3) << 2;     // 0,4,8,12
    const int tx = tid & 15;
    const int ty = tid >> 4;
    const int m0 = by * 64, n0 = bx * 64;

    float acc[4][4] = {};

    for (int k0 = 0; k0 < kIN; k0 += 16) {
        float4 av = *(const float4*)&A[(size_t)(m0 + r) * kIN + k0 + kq];
        float4 bv = *(const float4*)&B[(size_t)(n0 + r) * kIN + k0 + kq];
        __syncthreads();   // protect previous iteration's reads
        As[kq + 0][r] = av.x; As[kq + 1][r] = av.y; As[kq + 2][r] = av.z; As[kq + 3][r] = av.w;
        Bs[kq + 0][r] = bv.x; Bs[kq + 1][r] = bv.y; Bs[kq + 2][r] = bv.z; Bs[kq + 3][r] = bv.w;
        __syncthreads();
        #pragma unroll
        for (int k = 0; k < 16; ++k) {
            float a0 = As[k][ty * 4 + 0], a1 = As[k][ty * 4 + 1];
            float a2 = As[k][ty * 4 + 2], a3 = As[k][ty * 4 + 3];
            float b0 = Bs[k][tx * 4 + 0], b1 = Bs[k][tx * 4 + 1];
            float b2 = Bs[k][tx * 4 + 2], b3 = Bs[k][tx * 4 + 3];
            acc[0][0] += a0 * b0; acc[0][1] += a0 * b1; acc[0][2] += a0 * b2; acc[0][3] += a0 * b3;
            acc[1][0] += a1 * b0; acc[1][1] += a1 * b1; acc[1][2] += a1 * b2; acc[1][3] += a1 * b3;
            acc[2][0] += a2 * b0; acc[2][1] += a2 * b1; acc[2][2] += a2 * b2; acc[2][3] += a2 * b3;
            acc[3][0] += a3 * b0; acc[3][1] += a3 * b1; acc[3][2] += a3 * b2; acc[3][3] += a3 * b3;
        }
    }

    #pragma unroll
    for (int i = 0; i < 4; ++i) {
        const int m = m0 + ty * 4 + i;
        #pragma unroll
        for (int j = 0; j < 4; ++j) {
            const int n = n0 + tx * 4 + j;
            C[(size_t)m * kG4 + n] = __float2bfloat16(acc[i][j] + bih[n] + bhh[n]);
        }
    }
}

// ---------------------------------------------------------------------------
// Kernel 2: persistent LSTM recurrence. 256 WGs x 256 threads, 1 WG/CU.
// Data-carrying sync (round 9, kept): h published as u64 (f32<<32)|(t+1).
// New this round:
//  - PARALLEL poll: all 8 words loaded per retry (1 round-trip, not 8).
//  - Per-wave gate-complete weight rows: wave w holds gates i,f,g,o for its
//    2 h-indices (jl = 2w, 2w+1). Gate collection via 4 __shfl, c-update and
//    publish per-wave -> no cross-wave gbuf, no second barrier.
//  - hl double-buffered in LDS: single barrier/step bounds WG-internal skew
//    to 1 step; writer (step t+1, buf (t+1)&1) never touches the buffer a
//    lagging wave reads (step t, buf t&1). Slot reuse in hbuf gated on tag
//    t+2 publication, which certifies consumption of t+1 (round-9 argument).
// ---------------------------------------------------------------------------
__global__ __launch_bounds__(256, 1) void k_lstm(const float* __restrict__ Whh,
                                                 const __hip_bfloat16* __restrict__ xp,
                                                 unsigned long long* __restrict__ hbuf, // [2][kH]
                                                 uint32_t* __restrict__ abortf,
                                                 __hip_bfloat16* __restrict__ hs)
{
    extern __shared__ char smem[];
    __hip_bfloat16* Wl  = (__hip_bfloat16*)smem;              // [32][kWP] bf16
    float*          hl2 = (float*)(smem + 32 * kWP * 2);      // [2][kH] fp32

    const int wg  = blockIdx.x;
    const int tid = threadIdx.x;
    const int w   = tid >> 6;   // wave id
    const int l   = tid & 63;
    const int hb  = wg * kHB;

    // ---- one-time: stage W_hh slice, per-wave gate-complete mapping ----
    // LDS row lr holds W_hh row (gate lr&3, h-local 2*(lr>>3) + ((lr>>2)&1))
    {
        const int lr = tid >> 3;
        const int g  = lr & 3;
        const int jl = 2 * (lr >> 3) + ((lr >> 2) & 1);
        const int cb = (tid & 7) * 256;
        const float* src = Whh + (size_t)(g * kH + hb + jl) * kH + cb;
        __hip_bfloat16* dst = Wl + (size_t)lr * kWP + cb;
        for (int c = 0; c < 256; c += 4) {
            float4 v = *(const float4*)(src + c);
            dst[c + 0] = __float2bfloat16(v.x);
            dst[c + 1] = __float2bfloat16(v.y);
            dst[c + 2] = __float2bfloat16(v.z);
            dst[c + 3] = __float2bfloat16(v.w);
        }
    }
    __syncthreads();

    const __hip_bfloat16* wrow = Wl + (size_t)(w * 8 + (l >> 3)) * kWP;
    const int kbase = (l & 7) * 8;
    const int jg = hb + 2 * w + (l >> 5);     // this half-wave's h index (global)
    float c_state = 0.0f;
    uint32_t budget = 0;                      // whole-kernel retry budget

    for (int t = 0; t < kSEQ; ++t) {
        // ---- issue this lane's 4 x_proj gate values early (retire under poll) ----
        const __hip_bfloat16* xr = xp + (size_t)t * kG4 + jg;
        const float xi = __bfloat162float(xr[0]);
        const float xf = __bfloat162float(xr[kH]);
        const float xg = __bfloat162float(xr[2 * kH]);
        const float xo = __bfloat162float(xr[3 * kH]);

        // ---- gather h_{t-1} into hl2[t&1]: 8 words/thread, PARALLEL poll ----
        float* hw = hl2 + (size_t)(t & 1) * kH + tid * 8;
        int dead = 0;
        if (t == 0) {
            #pragma unroll
            for (int j = 0; j < 8; ++j) hw[j] = 0.f;
        } else {
            const unsigned long long* src = hbuf + (size_t)((t - 1) & 1) * kH + tid * 8;
            const uint32_t tag = (uint32_t)t;
            unsigned long long v[8];
            for (;;) {
                #pragma unroll
                for (int j = 0; j < 8; ++j)
                    v[j] = __hip_atomic_load(src + j, __ATOMIC_RELAXED, __HIP_MEMORY_SCOPE_AGENT);
                bool ok = true;
                #pragma unroll
                for (int j = 0; j < 8; ++j) ok &= ((uint32_t)v[j] == tag);
                if (ok) break;
                if ((++budget & 15) == 0) {
                    if (__hip_atomic_load(abortf, __ATOMIC_RELAXED,
                                          __HIP_MEMORY_SCOPE_AGENT) != 0u) { dead = 1; break; }
                    if (budget > (1u << 21)) {   // whole-kernel bound -> poison abort
                        __hip_atomic_store(abortf, 1u, __ATOMIC_RELAXED,
                                           __HIP_MEMORY_SCOPE_AGENT);
                        dead = 1; break;
                    }
                }
            }
            #pragma unroll
            for (int j = 0; j < 8; ++j) hw[j] = __uint_as_float((uint32_t)(v[j] >> 32));
        }
        if (__syncthreads_or(dead)) return;   // single barrier/step; never hangs

        // ---- matvec: lane group r=l>>3 -> LDS row w*8+r; 32 iters x 8 MACs ----
        const float* hv = hl2 + (size_t)(t & 1) * kH;
        float acc = 0.f;
        #pragma unroll 8
        for (int it = 0; it < 32; ++it) {
            const int k = it * 64 + kbase;
            uint4 wv = *(const uint4*)(wrow + k);
            float4 h0 = *(const float4*)(hv + k);
            float4 h1 = *(const float4*)(hv + k + 4);
            acc += bflo(wv.x) * h0.x + bfhi(wv.x) * h0.y
                 + bflo(wv.y) * h0.z + bfhi(wv.y) * h0.w
                 + bflo(wv.z) * h1.x + bfhi(wv.z) * h1.y
                 + bflo(wv.w) * h1.z + bfhi(wv.w) * h1.w;
        }
        acc += __shfl_xor(acc, 1);
        acc += __shfl_xor(acc, 2);
        acc += __shfl_xor(acc, 4);   // every lane of each 8-group has its row sum

        // ---- collect 4 gates for this half-wave's h index; update; publish ----
        const int base = l & 32;
        const float gi = __shfl(acc, base + 0)  + xi;
        const float gf = __shfl(acc, base + 8)  + xf;
        const float gg = __shfl(acc, base + 16) + xg;
        const float go = __shfl(acc, base + 24) + xo;
        const float si = 1.f / (1.f + expf(-gi));
        const float sf = 1.f / (1.f + expf(-gf));
        const float tg = tanhf(gg);
        const float so = 1.f / (1.f + expf(-go));
        c_state = sf * c_state + si * tg;            // valid per half-wave
        const float hvv = so * tanhf(c_state);
        if ((l & 31) == 0) {
            hs[(size_t)t * kH + jg] = __float2bfloat16(hvv);
            const unsigned long long pv =
                ((unsigned long long)__float_as_uint(hvv) << 32) | (uint32_t)(t + 1);
            __hip_atomic_store(hbuf + (size_t)(t & 1) * kH + jg, pv,
                               __ATOMIC_RELAXED, __HIP_MEMORY_SCOPE_AGENT);
        }
        // no trailing barrier: tags + next step's single barrier self-synchronize
    }
}

// ---------------------------------------------------------------------------
// Kernel 3: out[t] = sigmoid(hs[t] . W_lin + b_lin). One wave per t.
// ---------------------------------------------------------------------------
__global__ __launch_bounds__(256) void k_out(const __hip_bfloat16* __restrict__ hs,
                                             const float* __restrict__ wlin,
                                             const float* __restrict__ blin,
                                             float* __restrict__ out)
{
    const int w = threadIdx.x >> 6, l = threadIdx.x & 63;
    const int t = blockIdx.x * 4 + w;
    const __hip_bfloat16* row = hs + (size_t)t * kH;
    float acc = 0.f;
    #pragma unroll
    for (int i = 0; i < 4; ++i) {
        const int k = i * 512 + l * 8;
        uint4 hv = *(const uint4*)(row + k);
        float4 w0 = *(const float4*)(wlin + k);
        float4 w1 = *(const float4*)(wlin + k + 4);
        acc += bflo(hv.x) * w0.x + bfhi(hv.x) * w0.y
             + bflo(hv.y) * w0.z + bfhi(hv.y) * w0.w
             + bflo(hv.z) * w1.x + bfhi(hv.z) * w1.y
             + bflo(hv.w) * w1.z + bfhi(hv.w) * w1.w;
    }
    #pragma unroll
    for (int s = 32; s >= 1; s >>= 1) acc += __shfl_xor(acc, s);
    if (l == 0) out[t] = 1.f / (1.f + expf(-(acc + blin[0])));
}

// ---------------------------------------------------------------------------
extern "C" void kernel_launch(void* const* d_in, const int* in_sizes, int n_in,
                              void* d_out, int out_size, void* d_ws, size_t ws_size,
                              hipStream_t stream)
{
    const float* input_seq = (const float*)d_in[0];
    const float* W_ih      = (const float*)d_in[1];
    const float* W_hh      = (const float*)d_in[2];
    const float* b_ih      = (const float*)d_in[3];
    const float* b_hh      = (const float*)d_in[4];
    const float* W_lin     = (const float*)d_in[5];
    const float* b_lin     = (const float*)d_in[6];
    float* out = (float*)d_out;
    char*  ws  = (char*)d_ws;

    unsigned long long* hbuf = (unsigned long long*)(ws + OFF_HBUF);
    uint32_t*           abf  = (uint32_t*)(ws + OFF_ABORT);
    __hip_bfloat16*     hs   = (__hip_bfloat16*)(ws + OFF_HS);
    __hip_bfloat16*     xpb  = (__hip_bfloat16*)(ws + OFF_XP);

    // zero hbuf tags + abort each call (harness does not re-poison between replays)
    hipMemsetAsync(ws, 0, 65536, stream);

    k_xproj<<<dim3(128 * 128), dim3(256), 0, stream>>>(input_seq, W_ih, b_ih, b_hh, xpb);

    constexpr int kLds = 32 * kWP * 2 + 2 * kH * 4;   // 148480 B
    hipFuncSetAttribute((const void*)k_lstm, hipFuncAttributeMaxDynamicSharedMemorySize, kLds);

    // Preferred: cooperative launch -> driver guarantees all 256 WGs co-resident,
    // so the tag-poll is provably live. Fallback: plain launch (whole-kernel
    // bounded spin + sticky abort still prevents any hang).
    {
        const float* a0 = W_hh; const __hip_bfloat16* a1 = xpb;
        unsigned long long* a2 = hbuf; uint32_t* a3 = abf; __hip_bfloat16* a4 = hs;
        void* args[5] = { &a0, &a1, &a2, &a3, &a4 };
        hipError_t ce = hipLaunchCooperativeKernel((const void*)k_lstm, dim3(kNB), dim3(256),
                                                   args, (unsigned)kLds, stream);
        if (ce != hipSuccess) {
            k_lstm<<<dim3(kNB), dim3(256), kLds, stream>>>(W_hh, xpb, hbuf, abf, hs);
        }
    }

    k_out<<<dim3(kSEQ / 4), dim3(256), 0, stream>>>(hs, W_lin, b_lin, out);
}